// Round 1
// baseline (65.467 us; speedup 1.0000x reference)
//
#include <hip/hip_runtime.h>

// steps = 65536, channels = 6, state = [pos(6), vel(6)]
// Closed form of the scan:
//   S_t = sum_{i<=t} a_i        (per channel)
//   W_t = sum_{i<=t} i * a_i    (per channel)
//   vel[t] = v0 + dt*S_t
//   pos[t] = p0 + dt*(t+1)*v0 + dt^2*((t+0.5)*S_t - W_t)
// Output layout: states [65536,12] flat, then actions [65536,6] flat.

#define STEPS    65536
#define NCH      6
#define NB       256
#define CHUNK    (STEPS / NB)    // 256 steps per block
#define PER_LANE (CHUNK / 64)    // 4 steps per lane
#define BLK      (NCH * 64)      // 6 waves: wave w <-> channel w

__global__ __launch_bounds__(BLK) void k_partial(const float* __restrict__ act,
                                                 double* __restrict__ bsum) {
    const int b    = blockIdx.x;
    const int c    = threadIdx.x >> 6;   // channel = wave id
    const int lane = threadIdx.x & 63;
    const int t0   = b * CHUNK + lane * PER_LANE;

    double sA = 0.0, sW = 0.0;
#pragma unroll
    for (int k = 0; k < PER_LANE; ++k) {
        const int   t = t0 + k;
        const float a = act[t * NCH + c];
        sA += (double)a;
        sW += (double)t * (double)a;
    }
#pragma unroll
    for (int off = 32; off > 0; off >>= 1) {
        sA += __shfl_down(sA, off, 64);
        sW += __shfl_down(sW, off, 64);
    }
    if (lane == 0) {
        bsum[(b * NCH + c) * 2 + 0] = sA;
        bsum[(b * NCH + c) * 2 + 1] = sW;
    }
}

__global__ __launch_bounds__(BLK) void k_final(const float* __restrict__ act,
                                               const float* __restrict__ x,
                                               const double* __restrict__ bsum,
                                               float* __restrict__ out) {
    const int b    = blockIdx.x;
    const int c    = threadIdx.x >> 6;
    const int lane = threadIdx.x & 63;

    // Exclusive prefix over preceding blocks for this channel.
    // NB=256 block partials, 4 per lane, then wave-reduce.
    double offA = 0.0, offW = 0.0;
    {
        double vA = 0.0, vW = 0.0;
#pragma unroll
        for (int j = 0; j < NB / 64; ++j) {
            const int l = lane * (NB / 64) + j;
            if (l < b) {
                vA += bsum[(l * NCH + c) * 2 + 0];
                vW += bsum[(l * NCH + c) * 2 + 1];
            }
        }
#pragma unroll
        for (int off = 32; off > 0; off >>= 1) {
            vA += __shfl_down(vA, off, 64);
            vW += __shfl_down(vW, off, 64);
        }
        offA = __shfl(vA, 0, 64);
        offW = __shfl(vW, 0, 64);
    }

    // Lane-local partial sums over its PER_LANE steps (keep values in regs).
    const int t0 = b * CHUNK + lane * PER_LANE;
    float av[PER_LANE];
    double sA = 0.0, sW = 0.0;
#pragma unroll
    for (int k = 0; k < PER_LANE; ++k) {
        const int   t = t0 + k;
        const float a = act[t * NCH + c];
        av[k] = a;
        sA += (double)a;
        sW += (double)t * (double)a;
    }

    // Inclusive wave scan (Hillis-Steele) of lane sums -> exclusive via -self.
    double iA = sA, iW = sW;
#pragma unroll
    for (int off = 1; off < 64; off <<= 1) {
        const double uA = __shfl_up(iA, off, 64);
        const double uW = __shfl_up(iW, off, 64);
        if (lane >= off) { iA += uA; iW += uW; }
    }
    double runA = offA + iA - sA;   // exclusive prefix S before t0
    double runW = offW + iW - sW;   // exclusive prefix W before t0

    const double dt  = (double)0.1f;   // match float32(0.1) bit pattern
    const double dt2 = dt * dt;
    const double p0  = (double)x[c];
    const double v0  = (double)x[6 + c];

#pragma unroll
    for (int k = 0; k < PER_LANE; ++k) {
        const int   t = t0 + k;
        const float a = av[k];
        runA += (double)a;
        runW += (double)t * (double)a;
        const double vel = v0 + dt * runA;
        const double pos = p0 + dt * (double)(t + 1) * v0
                         + dt2 * (((double)t + 0.5) * runA - runW);
        out[t * 12 + c]              = (float)pos;   // states[t][c]
        out[t * 12 + 6 + c]          = (float)vel;   // states[t][6+c]
        out[STEPS * 12 + t * NCH + c] = a;           // actions passthrough
    }
}

extern "C" void kernel_launch(void* const* d_in, const int* in_sizes, int n_in,
                              void* d_out, int out_size, void* d_ws, size_t ws_size,
                              hipStream_t stream) {
    const float* x       = (const float*)d_in[0];   // 12 floats: pos(6), vel(6)
    const float* actions = (const float*)d_in[1];   // [65536, 6]
    float*       out     = (float*)d_out;           // states(786432) + actions(393216)
    double*      bsum    = (double*)d_ws;           // NB*NCH*2 doubles = 24 KiB

    hipLaunchKernelGGL(k_partial, dim3(NB), dim3(BLK), 0, stream, actions, bsum);
    hipLaunchKernelGGL(k_final,   dim3(NB), dim3(BLK), 0, stream, actions, x, bsum, out);
}

// Round 2
// 62.456 us; speedup vs baseline: 1.0482x; 1.0482x over previous
//
#include <hip/hip_runtime.h>

// steps = 65536, channels = 6, state = [pos(6), vel(6)]
// Closed form of the scan:
//   S_t = sum_{i<=t} a_i        (per channel)
//   W_t = sum_{i<=t} i * a_i    (per channel)
//   vel[t] = v0 + dt*S_t
//   pos[t] = p0 + dt*(t+1)*v0 + dt^2*((t+0.5)*S_t - W_t)
// Output layout: states [65536,12] flat, then actions [65536,6] flat.
//
// All global IO is coalesced float4 via LDS staging. Wave w <-> channel w
// (6 waves / 384 threads). Within a block's 256-step chunk, the scan runs as
// 4 sequential 64-step wave-scans with lane <-> timestep (lane stride 1 in t),
// which keeps LDS bank conflicts at worst 4-8 way on a handful of accesses.

#define STEPS   65536
#define NCH     6
#define STATE   12
#define NB      256
#define CHUNK   (STEPS / NB)        // 256 steps per block
#define BLK     (NCH * 64)          // 384 threads = 6 waves
#define ACT_OFF (STEPS * STATE)     // float offset of actions region in out

__global__ __launch_bounds__(BLK) void k_partial(const float4* __restrict__ act4,
                                                 float4* __restrict__ outact4,
                                                 double* __restrict__ bsum) {
    __shared__ float sIn[CHUNK * NCH];          // 6 KiB
    const int b = blockIdx.x, tid = threadIdx.x;

    // Coalesced stage-in + actions passthrough (coalesced float4 store).
    float4 v = act4[b * (CHUNK * NCH / 4) + tid];
    outact4[b * (CHUNK * NCH / 4) + tid] = v;
    ((float4*)sIn)[tid] = v;
    __syncthreads();

    const int c = tid >> 6, lane = tid & 63;
    double sA = 0.0, sW = 0.0;
#pragma unroll
    for (int k = 0; k < 4; ++k) {
        const int   tl = k * 64 + lane;
        const float a  = sIn[tl * NCH + c];
        sA += (double)a;
        sW += (double)(b * CHUNK + tl) * (double)a;
    }
#pragma unroll
    for (int off = 32; off > 0; off >>= 1) {
        sA += __shfl_down(sA, off, 64);
        sW += __shfl_down(sW, off, 64);
    }
    if (lane == 0) {
        bsum[(b * NCH + c) * 2 + 0] = sA;
        bsum[(b * NCH + c) * 2 + 1] = sW;
    }
}

__global__ __launch_bounds__(BLK) void k_final(const float4* __restrict__ act4,
                                               const float* __restrict__ x,
                                               const double* __restrict__ bsum,
                                               float4* __restrict__ out4) {
    __shared__ float sIn[CHUNK * NCH];          // 6 KiB
    __shared__ float sOut[CHUNK * STATE];       // 12 KiB
    const int b = blockIdx.x, tid = threadIdx.x;

    ((float4*)sIn)[tid] = act4[b * (CHUNK * NCH / 4) + tid];
    __syncthreads();

    const int c = tid >> 6, lane = tid & 63;

    // Cross-block exclusive prefix for this channel (256 partials, 4/lane).
    double offA, offW;
    {
        double vA = 0.0, vW = 0.0;
#pragma unroll
        for (int k = 0; k < 4; ++k) {
            const int idx = k * 64 + lane;
            if (idx < b) {
                vA += bsum[(idx * NCH + c) * 2 + 0];
                vW += bsum[(idx * NCH + c) * 2 + 1];
            }
        }
#pragma unroll
        for (int off = 32; off > 0; off >>= 1) {
            vA += __shfl_down(vA, off, 64);
            vW += __shfl_down(vW, off, 64);
        }
        offA = __shfl(vA, 0, 64);
        offW = __shfl(vW, 0, 64);
    }

    const double dt  = (double)0.1f;   // match float32(0.1) bit pattern
    const double dt2 = dt * dt;
    const double p0  = (double)x[c];
    const double v0  = (double)x[NCH + c];

    double accA = offA, accW = offW;   // running totals before current 64-tile
#pragma unroll
    for (int k = 0; k < 4; ++k) {
        const int   tl = k * 64 + lane;
        const int   t  = b * CHUNK + tl;
        const float a  = sIn[tl * NCH + c];
        double iA = (double)a;
        double iW = (double)t * (double)a;
        // Inclusive 64-lane scan (lane <-> t, stride 1).
#pragma unroll
        for (int off = 1; off < 64; off <<= 1) {
            const double uA = __shfl_up(iA, off, 64);
            const double uW = __shfl_up(iW, off, 64);
            if (lane >= off) { iA += uA; iW += uW; }
        }
        const double runA = accA + iA;
        const double runW = accW + iW;
        const double vel = v0 + dt * runA;
        const double pos = p0 + dt * (double)(t + 1) * v0
                         + dt2 * (((double)t + 0.5) * runA - runW);
        sOut[tl * STATE + c]       = (float)pos;
        sOut[tl * STATE + NCH + c] = (float)vel;
        accA += __shfl(iA, 63, 64);    // add tile total
        accW += __shfl(iW, 63, 64);
    }
    __syncthreads();

    // Coalesced writeout of the 256x12 state chunk: 768 float4, 2/thread.
    const float4* so4 = (const float4*)sOut;
    out4[b * (CHUNK * STATE / 4) + tid]       = so4[tid];
    out4[b * (CHUNK * STATE / 4) + BLK + tid] = so4[BLK + tid];
}

extern "C" void kernel_launch(void* const* d_in, const int* in_sizes, int n_in,
                              void* d_out, int out_size, void* d_ws, size_t ws_size,
                              hipStream_t stream) {
    const float* x       = (const float*)d_in[0];   // 12 floats: pos(6), vel(6)
    const float* actions = (const float*)d_in[1];   // [65536, 6]
    float*       out     = (float*)d_out;           // states(786432) + actions(393216)
    double*      bsum    = (double*)d_ws;           // NB*NCH*2 doubles = 24 KiB

    hipLaunchKernelGGL(k_partial, dim3(NB), dim3(BLK), 0, stream,
                       (const float4*)actions, (float4*)(out + ACT_OFF), bsum);
    hipLaunchKernelGGL(k_final, dim3(NB), dim3(BLK), 0, stream,
                       (const float4*)actions, x, bsum, (float4*)out);
}